// Round 15
// baseline (47.701 us; speedup 1.0000x reference)
//
#include <hip/hip_runtime.h>

#define N_    32
#define CIN   128
#define H_    56
#define W_    56
#define HW_   (H_ * W_)
#define COUT  256
#define GROUPS 4
#define CPG   32      // in-channels per group
#define OPG   64      // out-channels per group
#define CDIM  64
#define HP    58      // padded spatial dim (1-px zero halo each side)

#define TH    8               // output rows per block
#define NT    28              // pixel tiles (14 per wave-half)
#define ROWB  (HP * CPG)      // bf16 per padded row = 1856 (3712 B)
#define ROW4  232             // dwordx4 per row (3712/16)
#define NHALO 12              // shared rows per (n,g): {7,8,15,16,...,47,48}

// fallback-path tile geometry (R2 kernel)
#define FB_TH   8
#define HALO_R (FB_TH + 2)
#define HALO_C (W_ + 2)
#define XPLANE (HALO_R * HALO_C)

typedef __bf16 bf16x8 __attribute__((ext_vector_type(8)));
typedef __bf16 bf16x2 __attribute__((ext_vector_type(2)));
typedef float  f32x4  __attribute__((ext_vector_type(4)));
typedef unsigned int u32x4 __attribute__((ext_vector_type(4)));

__device__ __forceinline__ uint packbf2(float a, float b) {
    bf16x2 v; v[0] = (__bf16)a; v[1] = (__bf16)b;
    return __builtin_bit_cast(unsigned int, v);
}

// ---------- K1: halo-row xpose (1536) + ctx (32) + wconv (36) ----------
// Transposes ONLY the 12 rows per (n,g) that serve as another block's halo
// (global rows r%8 in {0,7}, r in [7,48]). xt layout/swizzle identical to R13:
// row = [58 pixels][4 slots][8 ic] bf16, octet o of pixel pix at slot o^((pix>>1)&3).
__global__ __launch_bounds__(256) void pre_kernel(
    const float* __restrict__ x, const float* __restrict__ c,
    const float* __restrict__ wgt, const float* __restrict__ bias,
    const float* __restrict__ cw,
    __bf16* __restrict__ xt, float* __restrict__ gctx, __bf16* __restrict__ wbf)
{
    const int bid = blockIdx.x;
    const int tid = threadIdx.x;

    if (bid < NHALO * GROUPS * N_) {              // ---- halo xpose ----
        const int hsel = bid % NHALO;
        const int g    = (bid / NHALO) & (GROUPS - 1);
        const int n    = bid / (NHALO * GROUPS);
        const int r    = 7 + (hsel >> 1) * 8 + (hsel & 1);   // 7,8,15,16,...,47,48
        const int hh   = r + 1;                               // padded row index
        u32x4* drow4 = (u32x4*)(xt + ((size_t)(n * GROUPS + g) * HP + hh) * ROWB);
        __shared__ float t[CPG][57];
        const float* src = x + ((size_t)(n * CIN + g * CPG) * H_ + r) * W_;
        for (int j = tid; j < CPG * (W_ / 4); j += 256) {
            int ic = j / 14, q = j - ic * 14;
            f32x4 v = *(const f32x4*)&src[(size_t)ic * HW_ + q * 4];
            #pragma unroll
            for (int k = 0; k < 4; ++k) t[ic][q * 4 + k] = v[k];
        }
        __syncthreads();
        if (tid < ROW4) {
            int pix = tid >> 2;
            int oct = (tid & 3) ^ ((pix >> 1) & 3);
            int w = pix - 1;
            u32x4 o4 = {0u, 0u, 0u, 0u};
            if ((unsigned)w < (unsigned)W_) {
                #pragma unroll
                for (int dd = 0; dd < 4; ++dd)
                    o4[dd] = packbf2(t[oct * 8 + dd * 2][w], t[oct * 8 + dd * 2 + 1][w]);
            }
            drow4[tid] = o4;
        }
    } else if (bid < NHALO * GROUPS * N_ + N_) {  // ---- ctx ----
        const int n  = bid - NHALO * GROUPS * N_;
        const int oc = tid;
        const float* cn  = c  + n * CDIM;
        const float* cwo = cw + oc * CDIM;
        float s = bias[oc];
        #pragma unroll
        for (int d = 0; d < CDIM; ++d) s += cn[d] * cwo[d];
        gctx[n * COUT + oc] = s;
    } else {                                      // ---- wconv: bf16 [g][tap][oct][ocL][8] ----
        int j = (bid - (NHALO * GROUPS * N_ + N_)) * 256 + tid;
        int e   = j & 7;
        int r   = j >> 3;
        int ocL = r & 63;  r >>= 6;
        int o   = r & 3;   r >>= 2;               // ic octet
        int tap = r % 9;
        int g   = r / 9;
        int ic  = o * 8 + e;
        wbf[j] = (__bf16)wgt[((g * OPG + ocL) * CPG + ic) * 9 + tap];
    }
}

// ---------- K2: fused main — own-row transpose in-block + halo from xt ----------
// Per block: (1) early-issue halo loads (2 xt rows) into regs; (2) transpose its
// 8 interior x rows (float4 -> fp32 bounce -> packed/swizzled ds_write_b128) into
// x_lds rows 1..8; (3) ds_write halo rows 0/9 from regs; (4) R13 compute verbatim.
// Kills the 55MB xt round-trip for interior rows (~80% of it).
__global__ __launch_bounds__(256, 3) void conv_main(
    const float* __restrict__ x, const __bf16* __restrict__ xt,
    const __bf16* __restrict__ wbf, const float* __restrict__ gctx,
    float* __restrict__ out)
{
    __shared__ __align__(16) __bf16 x_lds[10 * ROWB];   // 37120 B
    __shared__ float tb[2][CPG][57];                    // 14592 B bounce

    const int ht  = blockIdx.x;   // 0..6  (8-row strip)
    const int g   = blockIdx.y;   // 0..3
    const int n   = blockIdx.z;   // 0..31
    const int tid = threadIdx.x;  // 0..255 (4 waves)
    const int h0  = ht * TH;

    const int lane = tid & 63;
    const int wv   = tid >> 6;
    const int l15  = lane & 15;
    const int kh4  = lane >> 4;      // ic octet / D pixel-quad group
    const int p2   = (wv & 1) * 2;   // oc-tile pair base (0 or 2)
    const int ph   = wv >> 1;        // pixel half (14 tiles each)

    // ---- (1) halo rows (padded h0 and h0+9) -> regs, issued FIRST ----
    u32x4 halo0 = {0u,0u,0u,0u}, halo1 = {0u,0u,0u,0u};
    if (tid < ROW4) {
        const u32x4* x0 = (const u32x4*)(xt + ((size_t)(n * GROUPS + g) * HP + h0) * ROWB);
        const u32x4* x9 = (const u32x4*)(xt + ((size_t)(n * GROUPS + g) * HP + h0 + 9) * ROWB);
        if (ht > 0) halo0 = x0[tid];
        if (ht < 6) halo1 = x9[tid];
    }

    // ---- w-frag + ctx loads issued here (latency hides under transpose) ----
    u32x4 a[2][9];
    {
        const __bf16* wgb = wbf + (size_t)g * (9 * 4 * OPG * 8);
        #pragma unroll
        for (int i = 0; i < 2; ++i)
            #pragma unroll
            for (int tap = 0; tap < 9; ++tap)
                a[i][tap] = *(const u32x4*)&wgb[(((tap * 4 + kh4) * OPG) + (p2 + i) * 16 + l15) * 8];
    }
    float ctxv[2];
    #pragma unroll
    for (int i = 0; i < 2; ++i)
        ctxv[i] = gctx[n * COUT + g * OPG + (p2 + i) * 16 + l15];

    // ---- (2) transpose own 8 rows (global h0..h0+7) -> x_lds rows 1..8 ----
    const float* xg = x + ((size_t)(n * CIN + g * CPG) * H_ + h0) * W_;
    #pragma unroll 1
    for (int rp = 0; rp < 4; ++rp) {            // 2 rows per round
        for (int j = tid; j < 2 * CPG * 14; j += 256) {     // 896 float4 loads
            int rr = j / (CPG * 14);
            int k  = j - rr * (CPG * 14);
            int ic = k / 14, q = k - ic * 14;
            f32x4 v = *(const f32x4*)&xg[(size_t)ic * HW_ + (rp * 2 + rr) * W_ + q * 4];
            #pragma unroll
            for (int e = 0; e < 4; ++e) tb[rr][ic][q * 4 + e] = v[e];
        }
        __syncthreads();
        for (int j = tid; j < 2 * ROW4; j += 256) {         // 464 packed ds_write_b128
            int rr = j / ROW4;
            int t2 = j - rr * ROW4;
            int pix = t2 >> 2;
            int oct = (t2 & 3) ^ ((pix >> 1) & 3);
            int w = pix - 1;
            u32x4 o4 = {0u, 0u, 0u, 0u};
            if ((unsigned)w < (unsigned)W_) {
                #pragma unroll
                for (int dd = 0; dd < 4; ++dd)
                    o4[dd] = packbf2(tb[rr][oct * 8 + dd * 2][w], tb[rr][oct * 8 + dd * 2 + 1][w]);
            }
            ((u32x4*)&x_lds[(size_t)(1 + rp * 2 + rr) * ROWB])[t2] = o4;
        }
        __syncthreads();
    }

    // ---- (3) halo rows from regs -> x_lds rows 0 and 9 ----
    if (tid < ROW4) {
        ((u32x4*)&x_lds[0])[tid]                  = halo0;
        ((u32x4*)&x_lds[(size_t)9 * ROWB])[tid]   = halo1;
    }
    // pin w-frags here (materialize while transpose drained latency)
    #pragma unroll
    for (int i = 0; i < 2; ++i)
        #pragma unroll
        for (int tap = 0; tap < 9; ++tap)
            asm volatile("" : "+v"(a[i][tap]));
    __syncthreads();

    // ---- (4) compute: R13 verbatim (swapped-operand MFMA, dwordx4 stores) ----
    float* outb0 = out + ((size_t)n * COUT + g * OPG + p2 * 16 + l15) * HW_ + h0 * W_;
    float* outb1 = outb0 + (size_t)16 * HW_;

    #pragma unroll 1
    for (int t = ph * 14; t < ph * 14 + 14; ++t) {
        int p  = t * 16 + l15;           // A-row pixel for LDS read
        int pr = p / W_;
        int pc = p - pr * W_;
        f32x4 acc0 = {ctxv[0], ctxv[0], ctxv[0], ctxv[0]};
        f32x4 acc1 = {ctxv[1], ctxv[1], ctxv[1], ctxv[1]};
        #pragma unroll
        for (int kh = 0; kh < 3; ++kh) {
            #pragma unroll
            for (int kw = 0; kw < 3; ++kw) {
                int pix = pc + kw;
                int idx = (pr + kh) * ROWB + pix * CPG + ((kh4 ^ ((pix >> 1) & 3)) << 3);
                const bf16x8 b = *(const bf16x8*)&x_lds[idx];
                acc0 = __builtin_amdgcn_mfma_f32_16x16x32_bf16(
                           b, __builtin_bit_cast(bf16x8, a[0][kh * 3 + kw]), acc0, 0, 0, 0);
                acc1 = __builtin_amdgcn_mfma_f32_16x16x32_bf16(
                           b, __builtin_bit_cast(bf16x8, a[1][kh * 3 + kw]), acc1, 0, 0, 0);
            }
        }
        int p0 = t * 16 + kh4 * 4;
        *(f32x4*)&outb0[p0] = acc0;
        *(f32x4*)&outb1[p0] = acc1;
    }
}

// ---------- fallback (R2 structure) if workspace can't hold xt ----------
__global__ void ctx_kernel_fb(const float* __restrict__ c, const float* __restrict__ bias,
                              const float* __restrict__ cw, float* __restrict__ gctx) {
    const int n  = blockIdx.x;
    const int oc = threadIdx.x;
    const float* cn  = c  + n * CDIM;
    const float* cwo = cw + oc * CDIM;
    float s = bias[oc];
    #pragma unroll
    for (int d = 0; d < CDIM; ++d) s += cn[d] * cwo[d];
    gctx[n * COUT + oc] = s;
}
__global__ void wconv_kernel_fb(const float* __restrict__ wgt, __bf16* __restrict__ wbf) {
    int j = blockIdx.x * 256 + threadIdx.x;
    int e   = j & 7;
    int r   = j >> 3;
    int ocL = r & 63;  r >>= 6;
    int o   = r & 3;   r >>= 2;
    int tap = r % 9;
    int g   = r / 9;
    int ic  = o * 8 + e;
    wbf[j] = (__bf16)wgt[((g * OPG + ocL) * CPG + ic) * 9 + tap];
}
__global__ __launch_bounds__(512, 4) void ctx_conv_fb(
    const float* __restrict__ x, const __bf16* __restrict__ wbf,
    const float* __restrict__ gctx, float* __restrict__ out)
{
    __shared__ __align__(16) __bf16 x_lds[XPLANE][CPG];
    const int ht  = blockIdx.x;
    const int g   = blockIdx.y;
    const int n   = blockIdx.z;
    const int tid = threadIdx.x;
    const int h0  = ht * FB_TH;
    const int wv   = tid >> 6;
    const int lane = tid & 63;
    const int l15  = lane & 15;
    const int kh4  = lane >> 4;
    const int p2   = (wv & 1) * 2;
    const int pq   = wv >> 1;

    bf16x8 a[2][9];
    {
        const __bf16* wgb = wbf + (size_t)g * (9 * 4 * OPG * 8);
        #pragma unroll
        for (int i = 0; i < 2; ++i)
            #pragma unroll
            for (int tap = 0; tap < 9; ++tap)
                a[i][tap] = *(const bf16x8*)&wgb[(((tap * 4 + kh4) * OPG) + (p2 + i) * 16 + l15) * 8];
    }
    float ctxv[2][4];
    #pragma unroll
    for (int i = 0; i < 2; ++i)
        #pragma unroll
        for (int r = 0; r < 4; ++r)
            ctxv[i][r] = gctx[n * COUT + g * OPG + (p2 + i) * 16 + kh4 * 4 + r];
    {
        const float* xg = x + ((size_t)n * CIN + g * CPG) * HW_;
        for (int j = tid; j < 4 * XPLANE; j += 512) {
            int pix = j >> 2;
            int oct = j & 3;
            int hr = pix / HALO_C;
            int wc = pix - hr * HALO_C;
            int hg  = h0 - 1 + hr;
            int wg2 = wc - 1;
            bool valid = ((unsigned)hg < (unsigned)H_) && ((unsigned)wg2 < (unsigned)W_);
            const float* src = xg + (size_t)(oct * 8) * HW_ + hg * W_ + wg2;
            bf16x8 v;
            #pragma unroll
            for (int e = 0; e < 8; ++e)
                v[e] = (__bf16)(valid ? src[(size_t)e * HW_] : 0.f);
            *(bf16x8*)&x_lds[pix][oct * 8] = v;
        }
    }
    __syncthreads();
    float* outb = out + ((size_t)n * COUT + g * OPG + p2 * 16 + kh4 * 4) * HW_ + h0 * W_;
    #pragma unroll 1
    for (int t = pq * 7; t < pq * 7 + 7; ++t) {
        int p  = t * 16 + l15;
        int pr = p / W_;
        int pc = p - pr * W_;
        f32x4 acc0 = {0.f, 0.f, 0.f, 0.f};
        f32x4 acc1 = {0.f, 0.f, 0.f, 0.f};
        #pragma unroll
        for (int kh = 0; kh < 3; ++kh) {
            #pragma unroll
            for (int kw = 0; kw < 3; ++kw) {
                const bf16x8 b = *(const bf16x8*)&x_lds[(pr + kh) * HALO_C + (pc + kw)][kh4 * 8];
                acc0 = __builtin_amdgcn_mfma_f32_16x16x32_bf16(a[0][kh * 3 + kw], b, acc0, 0, 0, 0);
                acc1 = __builtin_amdgcn_mfma_f32_16x16x32_bf16(a[1][kh * 3 + kw], b, acc1, 0, 0, 0);
            }
        }
        #pragma unroll
        for (int r = 0; r < 4; ++r)
            outb[(size_t)r * HW_ + p] = acc0[r] + ctxv[0][r];
        #pragma unroll
        for (int r = 0; r < 4; ++r)
            outb[(size_t)(16 + r) * HW_ + p] = acc1[r] + ctxv[1][r];
    }
}

extern "C" void kernel_launch(void* const* d_in, const int* in_sizes, int n_in,
                              void* d_out, int out_size, void* d_ws, size_t ws_size,
                              hipStream_t stream) {
    const float* x    = (const float*)d_in[0];
    const float* c    = (const float*)d_in[1];
    const float* wgt  = (const float*)d_in[2];
    const float* bias = (const float*)d_in[3];
    const float* cw   = (const float*)d_in[4];
    float* out = (float*)d_out;

    const size_t XT_BYTES   = (size_t)N_ * GROUPS * HP * HP * CPG * 2;   // 27,557,888
    const size_t GCTX_BYTES = (size_t)N_ * COUT * 4;                     // 32,768
    const size_t WBF_BYTES  = (size_t)COUT * CPG * 9 * 2;                // 147,456
    const size_t NEEDED     = XT_BYTES + GCTX_BYTES + WBF_BYTES;

    if (ws_size >= NEEDED) {
        __bf16* xt   = (__bf16*)d_ws;
        float*  gctx = (float*)((char*)d_ws + XT_BYTES);
        __bf16* wbf  = (__bf16*)((char*)d_ws + XT_BYTES + GCTX_BYTES);

        const int nxp  = NHALO * GROUPS * N_;                     // 1536
        const int npre = nxp + N_ + (COUT * CPG * 9) / 256;       // +32 +36 = 1604
        pre_kernel<<<dim3(npre), 256, 0, stream>>>(x, c, wgt, bias, cw, xt, gctx, wbf);

        dim3 grid(H_ / TH, GROUPS, N_);   // (7, 4, 32) = 896 blocks x 256 thr
        conv_main<<<grid, 256, 0, stream>>>(x, xt, wbf, gctx, out);
    } else {
        float*  gctx = (float*)d_ws;
        __bf16* wbf  = (__bf16*)((char*)d_ws + 32768);
        ctx_kernel_fb<<<dim3(N_), 256, 0, stream>>>(c, bias, cw, gctx);
        wconv_kernel_fb<<<dim3((COUT * CPG * 9) / 256), 256, 0, stream>>>(wgt, wbf);
        dim3 grid(H_ / FB_TH, GROUPS, N_);
        ctx_conv_fb<<<grid, 512, 0, stream>>>(x, wbf, gctx, out);
    }
}